// Round 1
// baseline (1103.581 us; speedup 1.0000x reference)
//
#include <hip/hip_runtime.h>

typedef __attribute__((ext_vector_type(8))) short s16x8;
typedef __attribute__((ext_vector_type(4))) float f32x4;

static __device__ __forceinline__ short f2bf(float f) {
    unsigned u = __builtin_bit_cast(unsigned, f);
    u = (u + 0x7FFFu + ((u >> 16) & 1u)) >> 16;
    return (short)u;
}
static __device__ __forceinline__ float bf2f(short h) {
    unsigned u = ((unsigned)(unsigned short)h) << 16;
    return __builtin_bit_cast(float, u);
}

// ---------------- transpose + fp32->bf16 convert:  W[K][N] f32 -> Wt[N][K] bf16
__global__ __launch_bounds__(256) void transpose_convert(
    const float* __restrict__ W, short* __restrict__ Wt, int K, int N)
{
    __shared__ float tile[32][33];
    const int bx = blockIdx.x * 32;  // N
    const int by = blockIdx.y * 32;  // K
    const int tx = threadIdx.x;      // 0..31
    const int ty = threadIdx.y;      // 0..7
    for (int i = 0; i < 32; i += 8)
        tile[ty + i][tx] = W[(size_t)(by + ty + i) * N + bx + tx];
    __syncthreads();
    for (int i = 0; i < 32; i += 8)
        Wt[(size_t)(bx + ty + i) * K + by + tx] = f2bf(tile[tx][ty + i]);
}

// ---------------- LayerNorm: x[8192][768] f32 -> out bf16
__global__ __launch_bounds__(256) void layernorm_kernel(
    const float* __restrict__ x, const float* __restrict__ g,
    const float* __restrict__ b, short* __restrict__ out)
{
    const int row = blockIdx.x;
    const float* xr = x + (size_t)row * 768;
    const int t = threadIdx.x;
    float v0 = xr[t], v1 = xr[t + 256], v2 = xr[t + 512];
    __shared__ float red[4];

    float s = v0 + v1 + v2;
    for (int off = 32; off >= 1; off >>= 1) s += __shfl_down(s, off, 64);
    if ((t & 63) == 0) red[t >> 6] = s;
    __syncthreads();
    const float mean = (red[0] + red[1] + red[2] + red[3]) * (1.0f / 768.0f);
    const float d0 = v0 - mean, d1 = v1 - mean, d2 = v2 - mean;
    __syncthreads();
    float ss = d0 * d0 + d1 * d1 + d2 * d2;
    for (int off = 32; off >= 1; off >>= 1) ss += __shfl_down(ss, off, 64);
    if ((t & 63) == 0) red[t >> 6] = ss;
    __syncthreads();
    const float var = (red[0] + red[1] + red[2] + red[3]) * (1.0f / 768.0f);
    const float rstd = rsqrtf(var + 1e-5f);
    out[(size_t)row * 768 + t]       = f2bf(d0 * rstd * g[t] + b[t]);
    out[(size_t)row * 768 + t + 256] = f2bf(d1 * rstd * g[t + 256] + b[t + 256]);
    out[(size_t)row * 768 + t + 512] = f2bf(d2 * rstd * g[t + 512] + b[t + 512]);
}

// ---------------- GEMM: C[M][N] = A[M][K](bf16) * Bt[N][K](bf16)^T + bias
// MODE 0: out bf16 = acc + bias
// MODE 1: out f32  = acc + bias + res
// MODE 2: out bf16 = gelu(acc + bias)   (exact, erf)
template <int MODE>
__global__ __launch_bounds__(256) void gemm_bt(
    const short* __restrict__ A, const short* __restrict__ Bt,
    const float* __restrict__ bias, const float* __restrict__ res,
    void* __restrict__ out, int M, int N, int K)
{
    __shared__ __align__(16) short As[128][40];
    __shared__ __align__(16) short Bs[128][40];

    const int t = threadIdx.x;
    const int l = t & 63;
    const int w = t >> 6;
    const int wr = (w >> 1) * 64;
    const int wc = (w & 1) * 64;
    const int tm = blockIdx.y * 128;
    const int tn = blockIdx.x * 128;

    const int lr = t >> 2;         // staging row 0..63
    const int lc = (t & 3) * 8;    // staging col 0/8/16/24

    const int fr = l & 15;
    const int kq = (l >> 4) * 8;

    f32x4 acc[4][4] = {};

    for (int k0 = 0; k0 < K; k0 += 32) {
        *(s16x8*)&As[lr][lc]      = *(const s16x8*)(A + (size_t)(tm + lr) * K + k0 + lc);
        *(s16x8*)&As[lr + 64][lc] = *(const s16x8*)(A + (size_t)(tm + lr + 64) * K + k0 + lc);
        *(s16x8*)&Bs[lr][lc]      = *(const s16x8*)(Bt + (size_t)(tn + lr) * K + k0 + lc);
        *(s16x8*)&Bs[lr + 64][lc] = *(const s16x8*)(Bt + (size_t)(tn + lr + 64) * K + k0 + lc);
        __syncthreads();

        s16x8 af[4], bfr[4];
        for (int m = 0; m < 4; m++) af[m]  = *(const s16x8*)&As[wr + m * 16 + fr][kq];
        for (int n = 0; n < 4; n++) bfr[n] = *(const s16x8*)&Bs[wc + n * 16 + fr][kq];
        for (int m = 0; m < 4; m++)
            for (int n = 0; n < 4; n++)
                acc[m][n] = __builtin_amdgcn_mfma_f32_16x16x32_bf16(af[m], bfr[n], acc[m][n], 0, 0, 0);
        __syncthreads();
    }

    const int fq = (l >> 4) * 4;
    for (int m = 0; m < 4; m++) {
        for (int n = 0; n < 4; n++) {
            const int col = tn + wc + n * 16 + fr;
            const float bv = bias[col];
            for (int j = 0; j < 4; j++) {
                const int row = tm + wr + m * 16 + fq + j;
                float v = acc[m][n][j] + bv;
                if (MODE == 2) v = 0.5f * v * (1.0f + erff(v * 0.70710678118f));
                if (MODE == 1) {
                    ((float*)out)[(size_t)row * N + col] = v + res[(size_t)row * N + col];
                } else {
                    ((short*)out)[(size_t)row * N + col] = f2bf(v);
                }
            }
        }
    }
}

// ---------------- Flash attention: qkv[8192][2304] bf16 -> out[8192][768] bf16
// grid: (16 q-tiles, 96 b*h), block 256 (4 waves, each owns 16 q-rows)
__global__ __launch_bounds__(256) void attn_kernel(
    const short* __restrict__ qkv, short* __restrict__ out)
{
    const int qt = blockIdx.x;
    const int bh = blockIdx.y;
    const int b = bh / 12, h = bh % 12;

    __shared__ __align__(16) short Qs[64][72];
    __shared__ __align__(16) short Ks[64][72];
    __shared__ __align__(16) short Vt[64][72];
    __shared__ __align__(16) short Ps[64][72];

    const int t = threadIdx.x;
    const int l = t & 63;
    const int w = t >> 6;
    const int sr = t >> 3;        // 0..31
    const int sc = (t & 7) * 8;   // 0..56

    // stage Q once
    {
        const size_t base = ((size_t)(b * 1024 + qt * 64 + sr)) * 2304 + h * 64 + sc;
        *(s16x8*)&Qs[sr][sc]      = *(const s16x8*)(qkv + base);
        *(s16x8*)&Qs[sr + 32][sc] = *(const s16x8*)(qkv + base + (size_t)32 * 2304);
    }

    f32x4 acc_o[4] = {};
    float m_run[4] = {-1e30f, -1e30f, -1e30f, -1e30f};
    float l_run[4] = {0.f, 0.f, 0.f, 0.f};

    const int fr = l & 15;
    const int kq = (l >> 4) * 8;
    const int fq = (l >> 4) * 4;
    const float scale = 0.125f;  // 64^-0.5

    for (int kt = 0; kt < 16; kt++) {
        __syncthreads();
        // stage K tile and transposed V tile
        {
            const size_t kbase = ((size_t)(b * 1024 + kt * 64 + sr)) * 2304 + 768 + h * 64 + sc;
            *(s16x8*)&Ks[sr][sc]      = *(const s16x8*)(qkv + kbase);
            *(s16x8*)&Ks[sr + 32][sc] = *(const s16x8*)(qkv + kbase + (size_t)32 * 2304);
            const size_t vbase = kbase + 768;
            s16x8 v0 = *(const s16x8*)(qkv + vbase);
            s16x8 v1 = *(const s16x8*)(qkv + vbase + (size_t)32 * 2304);
            for (int i = 0; i < 8; i++) {
                Vt[sc + i][sr]      = v0[i];
                Vt[sc + i][sr + 32] = v1[i];
            }
        }
        __syncthreads();

        // S = Q K^T for this wave's 16 q-rows x 64 keys
        s16x8 qa0 = *(const s16x8*)&Qs[w * 16 + fr][kq];
        s16x8 qa1 = *(const s16x8*)&Qs[w * 16 + fr][32 + kq];
        f32x4 s[4];
        for (int n = 0; n < 4; n++) {
            s16x8 kb0 = *(const s16x8*)&Ks[n * 16 + fr][kq];
            s16x8 kb1 = *(const s16x8*)&Ks[n * 16 + fr][32 + kq];
            f32x4 sv = {};
            sv = __builtin_amdgcn_mfma_f32_16x16x32_bf16(qa0, kb0, sv, 0, 0, 0);
            sv = __builtin_amdgcn_mfma_f32_16x16x32_bf16(qa1, kb1, sv, 0, 0, 0);
            s[n] = sv;
        }

        // online softmax; lane handles rows fq+j, keys spread over 16 lanes x 4 frags
        float p[4][4];
        for (int j = 0; j < 4; j++) {
            float mx = fmaxf(fmaxf(s[0][j], s[1][j]), fmaxf(s[2][j], s[3][j])) * scale;
            for (int off = 1; off < 16; off <<= 1)
                mx = fmaxf(mx, __shfl_xor(mx, off, 64));
            const float mnew = fmaxf(m_run[j], mx);
            float sum = 0.f;
            for (int n = 0; n < 4; n++) {
                const float pv = __expf(s[n][j] * scale - mnew);
                p[n][j] = pv;
                sum += pv;
            }
            for (int off = 1; off < 16; off <<= 1)
                sum += __shfl_xor(sum, off, 64);
            const float alpha = __expf(m_run[j] - mnew);
            l_run[j] = l_run[j] * alpha + sum;
            m_run[j] = mnew;
            for (int n = 0; n < 4; n++) acc_o[n][j] *= alpha;
        }

        // P -> LDS (A-fragment layout round-trip)
        for (int n = 0; n < 4; n++)
            for (int j = 0; j < 4; j++)
                Ps[w * 16 + fq + j][n * 16 + fr] = f2bf(p[n][j]);
        __syncthreads();

        // O += P V  (Vt[d][k] gives contiguous-k B fragments)
        s16x8 pa0 = *(const s16x8*)&Ps[w * 16 + fr][kq];
        s16x8 pa1 = *(const s16x8*)&Ps[w * 16 + fr][32 + kq];
        for (int n = 0; n < 4; n++) {
            s16x8 vb0 = *(const s16x8*)&Vt[n * 16 + fr][kq];
            s16x8 vb1 = *(const s16x8*)&Vt[n * 16 + fr][32 + kq];
            acc_o[n] = __builtin_amdgcn_mfma_f32_16x16x32_bf16(pa0, vb0, acc_o[n], 0, 0, 0);
            acc_o[n] = __builtin_amdgcn_mfma_f32_16x16x32_bf16(pa1, vb1, acc_o[n], 0, 0, 0);
        }
    }

    for (int n = 0; n < 4; n++)
        for (int j = 0; j < 4; j++) {
            const int qrow = b * 1024 + qt * 64 + w * 16 + fq + j;
            const int col = h * 64 + n * 16 + fr;
            out[(size_t)qrow * 768 + col] = f2bf(acc_o[n][j] / l_run[j]);
        }
}

extern "C" void kernel_launch(void* const* d_in, const int* in_sizes, int n_in,
                              void* d_out, int out_size, void* d_ws, size_t ws_size,
                              hipStream_t stream) {
    const float* x      = (const float*)d_in[0];
    const float* n1g    = (const float*)d_in[1];
    const float* n1b    = (const float*)d_in[2];
    const float* qkv_w  = (const float*)d_in[3];
    const float* qkv_b  = (const float*)d_in[4];
    const float* proj_w = (const float*)d_in[5];
    const float* proj_b = (const float*)d_in[6];
    const float* n2g    = (const float*)d_in[7];
    const float* n2b    = (const float*)d_in[8];
    const float* fc1_w  = (const float*)d_in[9];
    const float* fc1_b  = (const float*)d_in[10];
    const float* fc2_w  = (const float*)d_in[11];
    const float* fc2_b  = (const float*)d_in[12];
    float* out = (float*)d_out;

    char* ws = (char*)d_ws;
    short* qkv_wT = (short*)(ws + 0);                    // [2304][768] bf16
    short* proj_wT = (short*)(ws + 3538944);             // [768][768]
    short* fc1_wT = (short*)(ws + 4718592);              // [3072][768]
    short* fc2_wT = (short*)(ws + 9437184);              // [768][3072]
    short* bufA = (short*)(ws + 14155776);               // 8192x768 bf16 (ln1/attn_out/ln2)
    short* bufB = (short*)(ws + 26738688);               // 8192x3072 bf16 (qkv / h1)
    float* bufC = (float*)(ws + 77070336);               // 8192x768 f32 (x1)

    const dim3 tb(32, 8);
    transpose_convert<<<dim3(2304 / 32, 768 / 32), tb, 0, stream>>>(qkv_w, qkv_wT, 768, 2304);
    transpose_convert<<<dim3(768 / 32, 768 / 32),  tb, 0, stream>>>(proj_w, proj_wT, 768, 768);
    transpose_convert<<<dim3(3072 / 32, 768 / 32), tb, 0, stream>>>(fc1_w, fc1_wT, 768, 3072);
    transpose_convert<<<dim3(768 / 32, 3072 / 32), tb, 0, stream>>>(fc2_w, fc2_wT, 3072, 768);

    layernorm_kernel<<<8192, 256, 0, stream>>>(x, n1g, n1b, bufA);

    gemm_bt<0><<<dim3(2304 / 128, 8192 / 128), 256, 0, stream>>>(
        bufA, qkv_wT, qkv_b, nullptr, bufB, 8192, 2304, 768);

    attn_kernel<<<dim3(16, 96), 256, 0, stream>>>(bufB, bufA);

    gemm_bt<1><<<dim3(768 / 128, 8192 / 128), 256, 0, stream>>>(
        bufA, proj_wT, proj_b, x, bufC, 8192, 768, 768);

    layernorm_kernel<<<8192, 256, 0, stream>>>(bufC, n2g, n2b, bufA);

    gemm_bt<2><<<dim3(3072 / 128, 8192 / 128), 256, 0, stream>>>(
        bufA, fc1_wT, fc1_b, nullptr, bufB, 8192, 3072, 768);

    gemm_bt<1><<<dim3(768 / 128, 8192 / 128), 256, 0, stream>>>(
        bufB, fc2_wT, fc2_b, bufC, out, 8192, 768, 3072);
}

// Round 2
// 386.588 us; speedup vs baseline: 2.8547x; 2.8547x over previous
//
#include <hip/hip_runtime.h>

typedef __attribute__((ext_vector_type(8))) short s16x8;
typedef __attribute__((ext_vector_type(4))) float f32x4;

static __device__ __forceinline__ short f2bf(float f) {
    unsigned u = __builtin_bit_cast(unsigned, f);
    u = (u + 0x7FFFu + ((u >> 16) & 1u)) >> 16;
    return (short)u;
}

__device__ __forceinline__ void gload16(const short* g, short* l) {
    __builtin_amdgcn_global_load_lds(
        (const __attribute__((address_space(1))) void*)g,
        (__attribute__((address_space(3))) void*)l,
        16, 0, 0);
}

// ---------------- transpose + fp32->bf16 convert:  W[K][N] f32 -> Wt[N][K] bf16
__global__ __launch_bounds__(256) void transpose_convert(
    const float* __restrict__ W, short* __restrict__ Wt, int K, int N)
{
    __shared__ float tile[32][33];
    const int bx = blockIdx.x * 32;  // N
    const int by = blockIdx.y * 32;  // K
    const int tx = threadIdx.x;      // 0..31
    const int ty = threadIdx.y;      // 0..7
    for (int i = 0; i < 32; i += 8)
        tile[ty + i][tx] = W[(size_t)(by + ty + i) * N + bx + tx];
    __syncthreads();
    for (int i = 0; i < 32; i += 8)
        Wt[(size_t)(bx + ty + i) * K + by + tx] = f2bf(tile[tx][ty + i]);
}

// ---------------- LayerNorm: x[8192][768] f32 -> out bf16
__global__ __launch_bounds__(256) void layernorm_kernel(
    const float* __restrict__ x, const float* __restrict__ g,
    const float* __restrict__ b, short* __restrict__ out)
{
    const int row = blockIdx.x;
    const float* xr = x + (size_t)row * 768;
    const int t = threadIdx.x;
    float v0 = xr[t], v1 = xr[t + 256], v2 = xr[t + 512];
    __shared__ float red[4];

    float s = v0 + v1 + v2;
    for (int off = 32; off >= 1; off >>= 1) s += __shfl_down(s, off, 64);
    if ((t & 63) == 0) red[t >> 6] = s;
    __syncthreads();
    const float mean = (red[0] + red[1] + red[2] + red[3]) * (1.0f / 768.0f);
    const float d0 = v0 - mean, d1 = v1 - mean, d2 = v2 - mean;
    __syncthreads();
    float ss = d0 * d0 + d1 * d1 + d2 * d2;
    for (int off = 32; off >= 1; off >>= 1) ss += __shfl_down(ss, off, 64);
    if ((t & 63) == 0) red[t >> 6] = ss;
    __syncthreads();
    const float var = (red[0] + red[1] + red[2] + red[3]) * (1.0f / 768.0f);
    const float rstd = rsqrtf(var + 1e-5f);
    out[(size_t)row * 768 + t]       = f2bf(d0 * rstd * g[t] + b[t]);
    out[(size_t)row * 768 + t + 256] = f2bf(d1 * rstd * g[t + 256] + b[t + 256]);
    out[(size_t)row * 768 + t + 512] = f2bf(d2 * rstd * g[t + 512] + b[t + 512]);
}

// ---------------- GEMM (m97 structure): C[M][N] = A[M][K](bf16) * Bt[N][K]^T + bias
// Linear LDS [128][32], staged via global_load_lds width=16, 2 barriers / K-step.
// MODE 0: out bf16 = acc + bias
// MODE 1: out f32  = acc + bias + res
// MODE 2: out bf16 = gelu(acc + bias)   (exact, erf)
template <int MODE>
__global__ __launch_bounds__(256) void gemm_bt(
    const short* __restrict__ A, const short* __restrict__ Bt,
    const float* __restrict__ bias, const float* __restrict__ res,
    void* __restrict__ out, int M, int N, int K)
{
    __shared__ __align__(16) short As[128 * 32];
    __shared__ __align__(16) short Bs[128 * 32];

    const int t = threadIdx.x;
    const int l = t & 63;
    const int w = t >> 6;
    const int wr = (w >> 1) * 64;
    const int wc = (w & 1) * 64;
    const int tm = blockIdx.y * 128;
    const int tn = blockIdx.x * 128;

    // staging: wave w owns LDS chunks {2w, 2w+1} of A and of B (1 KB each,
    // = 16 rows of 32 bf16). global_load_lds writes base + lane*16B; lane l
    // covers row l/4, cols (l%4)*8..+8 of the chunk.
    const int lrow = l >> 2;
    const int lcol = (l & 3) * 8;
    const int ca = w * 2;
    const short* aS0 = A  + (size_t)(tm + ca * 16 + lrow) * K + lcol;
    const short* aS1 = aS0 + (size_t)16 * K;
    const short* bS0 = Bt + (size_t)(tn + ca * 16 + lrow) * K + lcol;
    const short* bS1 = bS0 + (size_t)16 * K;
    short* lA0 = &As[ca * 512];
    short* lA1 = &As[ca * 512 + 512];
    short* lB0 = &Bs[ca * 512];
    short* lB1 = &Bs[ca * 512 + 512];

    const int fr = l & 15;
    const int kq = (l >> 4) * 8;

    f32x4 acc[4][4] = {};

    for (int k0 = 0; k0 < K; k0 += 32) {
        gload16(aS0 + k0, lA0);
        gload16(aS1 + k0, lA1);
        gload16(bS0 + k0, lB0);
        gload16(bS1 + k0, lB1);
        __syncthreads();   // drains vmcnt -> LDS tiles complete

        s16x8 af[4], bfr[4];
#pragma unroll
        for (int m = 0; m < 4; m++) af[m]  = *(const s16x8*)&As[(wr + m * 16 + fr) * 32 + kq];
#pragma unroll
        for (int n = 0; n < 4; n++) bfr[n] = *(const s16x8*)&Bs[(wc + n * 16 + fr) * 32 + kq];
#pragma unroll
        for (int m = 0; m < 4; m++)
#pragma unroll
            for (int n = 0; n < 4; n++)
                acc[m][n] = __builtin_amdgcn_mfma_f32_16x16x32_bf16(af[m], bfr[n], acc[m][n], 0, 0, 0);
        __syncthreads();   // protect LDS reuse next iter
    }

    const int fq = (l >> 4) * 4;
#pragma unroll
    for (int m = 0; m < 4; m++) {
#pragma unroll
        for (int n = 0; n < 4; n++) {
            const int col = tn + wc + n * 16 + fr;
            const float bv = bias[col];
#pragma unroll
            for (int j = 0; j < 4; j++) {
                const int row = tm + wr + m * 16 + fq + j;
                float v = acc[m][n][j] + bv;
                if (MODE == 2) v = 0.5f * v * (1.0f + erff(v * 0.70710678118f));
                if (MODE == 1) {
                    ((float*)out)[(size_t)row * N + col] = v + res[(size_t)row * N + col];
                } else {
                    ((short*)out)[(size_t)row * N + col] = f2bf(v);
                }
            }
        }
    }
}

// ---------------- Flash attention: qkv[8192][2304] bf16 -> out[8192][768] bf16
// grid: (16 q-tiles, 96 b*h), block 256 (4 waves, each owns 16 q-rows)
__global__ __launch_bounds__(256) void attn_kernel(
    const short* __restrict__ qkv, short* __restrict__ out)
{
    const int qt = blockIdx.x;
    const int bh = blockIdx.y;
    const int b = bh / 12, h = bh % 12;

    __shared__ __align__(16) short Qs[64][72];
    __shared__ __align__(16) short Ks[64][72];
    __shared__ __align__(16) short Vt[64][72];
    __shared__ __align__(16) short Ps[64][72];

    const int t = threadIdx.x;
    const int l = t & 63;
    const int w = t >> 6;
    const int sr = t >> 3;        // 0..31
    const int sc = (t & 7) * 8;   // 0..56

    const int fr = l & 15;
    const int kq = (l >> 4) * 8;
    const int fq = (l >> 4) * 4;
    const float scale = 0.125f;  // 64^-0.5

    // stage Q once, hoist fragments to registers
    {
        const size_t base = ((size_t)(b * 1024 + qt * 64 + sr)) * 2304 + h * 64 + sc;
        *(s16x8*)&Qs[sr][sc]      = *(const s16x8*)(qkv + base);
        *(s16x8*)&Qs[sr + 32][sc] = *(const s16x8*)(qkv + base + (size_t)32 * 2304);
    }
    __syncthreads();
    const s16x8 qa0 = *(const s16x8*)&Qs[w * 16 + fr][kq];
    const s16x8 qa1 = *(const s16x8*)&Qs[w * 16 + fr][32 + kq];

    f32x4 acc_o[4] = {};
    float m_run[4] = {-1e30f, -1e30f, -1e30f, -1e30f};
    float l_run[4] = {0.f, 0.f, 0.f, 0.f};

    for (int kt = 0; kt < 16; kt++) {
        __syncthreads();
        // stage K tile and transposed V tile
        {
            const size_t kbase = ((size_t)(b * 1024 + kt * 64 + sr)) * 2304 + 768 + h * 64 + sc;
            *(s16x8*)&Ks[sr][sc]      = *(const s16x8*)(qkv + kbase);
            *(s16x8*)&Ks[sr + 32][sc] = *(const s16x8*)(qkv + kbase + (size_t)32 * 2304);
            const size_t vbase = kbase + 768;
            s16x8 v0 = *(const s16x8*)(qkv + vbase);
            s16x8 v1 = *(const s16x8*)(qkv + vbase + (size_t)32 * 2304);
            for (int i = 0; i < 8; i++) {
                Vt[sc + i][sr]      = v0[i];
                Vt[sc + i][sr + 32] = v1[i];
            }
        }
        __syncthreads();

        // S = Q K^T for this wave's 16 q-rows x 64 keys
        f32x4 s[4];
#pragma unroll
        for (int n = 0; n < 4; n++) {
            s16x8 kb0 = *(const s16x8*)&Ks[n * 16 + fr][kq];
            s16x8 kb1 = *(const s16x8*)&Ks[n * 16 + fr][32 + kq];
            f32x4 sv = {};
            sv = __builtin_amdgcn_mfma_f32_16x16x32_bf16(qa0, kb0, sv, 0, 0, 0);
            sv = __builtin_amdgcn_mfma_f32_16x16x32_bf16(qa1, kb1, sv, 0, 0, 0);
            s[n] = sv;
        }

        // online softmax; lane handles rows fq+j, keys spread over 16 lanes x 4 frags
        float p[4][4];
#pragma unroll
        for (int j = 0; j < 4; j++) {
            float mx = fmaxf(fmaxf(s[0][j], s[1][j]), fmaxf(s[2][j], s[3][j])) * scale;
            for (int off = 1; off < 16; off <<= 1)
                mx = fmaxf(mx, __shfl_xor(mx, off, 64));
            const float mnew = fmaxf(m_run[j], mx);
            float sum = 0.f;
#pragma unroll
            for (int n = 0; n < 4; n++) {
                const float pv = __expf(s[n][j] * scale - mnew);
                p[n][j] = pv;
                sum += pv;
            }
            for (int off = 1; off < 16; off <<= 1)
                sum += __shfl_xor(sum, off, 64);
            const float alpha = __expf(m_run[j] - mnew);
            l_run[j] = l_run[j] * alpha + sum;
            m_run[j] = mnew;
#pragma unroll
            for (int n = 0; n < 4; n++) acc_o[n][j] *= alpha;
        }

        // P -> LDS (A-fragment layout round-trip); wave-local rows
#pragma unroll
        for (int n = 0; n < 4; n++)
#pragma unroll
            for (int j = 0; j < 4; j++)
                Ps[w * 16 + fq + j][n * 16 + fr] = f2bf(p[n][j]);
        __syncthreads();

        // O += P V  (Vt[d][k] gives contiguous-k B fragments)
        s16x8 pa0 = *(const s16x8*)&Ps[w * 16 + fr][kq];
        s16x8 pa1 = *(const s16x8*)&Ps[w * 16 + fr][32 + kq];
#pragma unroll
        for (int n = 0; n < 4; n++) {
            s16x8 vb0 = *(const s16x8*)&Vt[n * 16 + fr][kq];
            s16x8 vb1 = *(const s16x8*)&Vt[n * 16 + fr][32 + kq];
            acc_o[n] = __builtin_amdgcn_mfma_f32_16x16x32_bf16(pa0, vb0, acc_o[n], 0, 0, 0);
            acc_o[n] = __builtin_amdgcn_mfma_f32_16x16x32_bf16(pa1, vb1, acc_o[n], 0, 0, 0);
        }
    }

#pragma unroll
    for (int n = 0; n < 4; n++)
#pragma unroll
        for (int j = 0; j < 4; j++) {
            const int qrow = b * 1024 + qt * 64 + w * 16 + fq + j;
            const int col = h * 64 + n * 16 + fr;
            out[(size_t)qrow * 768 + col] = f2bf(acc_o[n][j] / l_run[j]);
        }
}

extern "C" void kernel_launch(void* const* d_in, const int* in_sizes, int n_in,
                              void* d_out, int out_size, void* d_ws, size_t ws_size,
                              hipStream_t stream) {
    const float* x      = (const float*)d_in[0];
    const float* n1g    = (const float*)d_in[1];
    const float* n1b    = (const float*)d_in[2];
    const float* qkv_w  = (const float*)d_in[3];
    const float* qkv_b  = (const float*)d_in[4];
    const float* proj_w = (const float*)d_in[5];
    const float* proj_b = (const float*)d_in[6];
    const float* n2g    = (const float*)d_in[7];
    const float* n2b    = (const float*)d_in[8];
    const float* fc1_w  = (const float*)d_in[9];
    const float* fc1_b  = (const float*)d_in[10];
    const float* fc2_w  = (const float*)d_in[11];
    const float* fc2_b  = (const float*)d_in[12];
    float* out = (float*)d_out;

    char* ws = (char*)d_ws;
    short* qkv_wT = (short*)(ws + 0);                    // [2304][768] bf16
    short* proj_wT = (short*)(ws + 3538944);             // [768][768]
    short* fc1_wT = (short*)(ws + 4718592);              // [3072][768]
    short* fc2_wT = (short*)(ws + 9437184);              // [768][3072]
    short* bufA = (short*)(ws + 14155776);               // 8192x768 bf16 (ln1/attn_out/ln2)
    short* bufB = (short*)(ws + 26738688);               // 8192x3072 bf16 (qkv / h1)
    float* bufC = (float*)(ws + 77070336);               // 8192x768 f32 (x1)

    const dim3 tb(32, 8);
    transpose_convert<<<dim3(2304 / 32, 768 / 32), tb, 0, stream>>>(qkv_w, qkv_wT, 768, 2304);
    transpose_convert<<<dim3(768 / 32, 768 / 32),  tb, 0, stream>>>(proj_w, proj_wT, 768, 768);
    transpose_convert<<<dim3(3072 / 32, 768 / 32), tb, 0, stream>>>(fc1_w, fc1_wT, 768, 3072);
    transpose_convert<<<dim3(768 / 32, 3072 / 32), tb, 0, stream>>>(fc2_w, fc2_wT, 3072, 768);

    layernorm_kernel<<<8192, 256, 0, stream>>>(x, n1g, n1b, bufA);

    gemm_bt<0><<<dim3(2304 / 128, 8192 / 128), 256, 0, stream>>>(
        bufA, qkv_wT, qkv_b, nullptr, bufB, 8192, 2304, 768);

    attn_kernel<<<dim3(16, 96), 256, 0, stream>>>(bufB, bufA);

    gemm_bt<1><<<dim3(768 / 128, 8192 / 128), 256, 0, stream>>>(
        bufA, proj_wT, proj_b, x, bufC, 8192, 768, 768);

    layernorm_kernel<<<8192, 256, 0, stream>>>(bufC, n2g, n2b, bufA);

    gemm_bt<2><<<dim3(3072 / 128, 8192 / 128), 256, 0, stream>>>(
        bufA, fc1_wT, fc1_b, nullptr, bufB, 8192, 3072, 768);

    gemm_bt<1><<<dim3(768 / 128, 8192 / 128), 256, 0, stream>>>(
        bufB, fc2_wT, fc2_b, bufC, out, 8192, 768, 3072);
}